// Round 1
// baseline (3161.034 us; speedup 1.0000x reference)
//
#include <hip/hip_runtime.h>
#include <hip/hip_bf16.h>

// GIN net: 3x { scatter-add aggr; h=(1+eps)x+aggr; Lin+ReLU; Lin+ReLU; BN(train) }
// then mean-pool per graph + 2-layer readout MLP.
// N=100000 nodes, E=1200000 edges, F_IN=16, H=64, G=1024 (G taken from out_size).

#define HD 64

// ---------------- scatter-add: aggr[dst] += x[src], vectorized float4 ----------------
__global__ void scatter_kernel(const float* __restrict__ x, const int* __restrict__ ei,
                               float* __restrict__ aggr, int E, int d, int shift) {
    int tid = blockIdx.x * blockDim.x + threadIdx.x;
    int total = E << shift;            // E * (d/4)
    if (tid >= total) return;
    int e = tid >> shift;
    int c = tid & ((1 << shift) - 1);
    int src = ei[e];
    int dst = ei[E + e];
    const float4 v = *reinterpret_cast<const float4*>(x + (size_t)src * d + (size_t)c * 4);
    float* a = aggr + (size_t)dst * d + (size_t)c * 4;
    unsafeAtomicAdd(a + 0, v.x);
    unsafeAtomicAdd(a + 1, v.y);
    unsafeAtomicAdd(a + 2, v.z);
    unsafeAtomicAdd(a + 3, v.w);
}

// ---------------- t = relu( ((1+eps)*x + aggr) @ Wa + ba ), Wa: [DIN,64] ----------------
template <int DIN>
__global__ void lin_a_kernel(const float* __restrict__ xin, const float* __restrict__ aggr,
                             const float* __restrict__ W, const float* __restrict__ b,
                             const float* __restrict__ epsp,
                             float* __restrict__ out, int N) {
    __shared__ float Ws[DIN * HD];
    for (int i = threadIdx.x; i < DIN * HD; i += blockDim.x) Ws[i] = W[i];
    __syncthreads();
    int tid = blockIdx.x * blockDim.x + threadIdx.x;
    int n = tid >> 6;
    int oc = tid & 63;
    if (n >= N) return;
    float e1 = 1.0f + epsp[0];
    float acc = b[oc];
    const float* xr = xin + (size_t)n * DIN;
    const float* ar = aggr + (size_t)n * DIN;
#pragma unroll
    for (int k = 0; k < DIN; k++) {
        float h = e1 * xr[k] + ar[k];
        acc = fmaf(h, Ws[k * HD + oc], acc);
    }
    out[(size_t)n * HD + oc] = fmaxf(acc, 0.0f);
}

// ---------------- h = relu( t @ Wb + bb ); accumulate per-channel sum/sumsq ----------------
__global__ void lin_b_stats_kernel(const float* __restrict__ t,
                                   const float* __restrict__ W, const float* __restrict__ b,
                                   float* __restrict__ h, float* __restrict__ stats, int N) {
    __shared__ float Ws[HD * HD];
    __shared__ float red[2][4][HD];
    for (int i = threadIdx.x; i < HD * HD; i += blockDim.x) Ws[i] = W[i];
    __syncthreads();
    const int ROWS = 32;
    int oc = threadIdx.x & 63;
    int slot = threadIdx.x >> 6;   // 0..3
    int base = blockIdx.x * ROWS;
    float s = 0.0f, s2 = 0.0f;
    for (int r = slot; r < ROWS; r += 4) {
        int n = base + r;
        if (n >= N) break;
        float acc = b[oc];
        const float* tr = t + (size_t)n * HD;
#pragma unroll 16
        for (int k = 0; k < HD; k++) acc = fmaf(tr[k], Ws[k * HD + oc], acc);
        acc = fmaxf(acc, 0.0f);
        h[(size_t)n * HD + oc] = acc;
        s += acc;
        s2 += acc * acc;
    }
    red[0][slot][oc] = s;
    red[1][slot][oc] = s2;
    __syncthreads();
    if (slot == 0) {
        float ts  = red[0][0][oc] + red[0][1][oc] + red[0][2][oc] + red[0][3][oc];
        float ts2 = red[1][0][oc] + red[1][1][oc] + red[1][2][oc] + red[1][3][oc];
        unsafeAtomicAdd(&stats[oc], ts);
        unsafeAtomicAdd(&stats[HD + oc], ts2);
    }
}

// ---------------- y = g*(h-mu)*rsqrt(var+eps)+be ----------------
__global__ void bn_kernel(const float* __restrict__ h, const float* __restrict__ stats,
                          const float* __restrict__ g, const float* __restrict__ be,
                          float* __restrict__ y, int N) {
    int tid = blockIdx.x * blockDim.x + threadIdx.x;
    if (tid >= N * HD) return;
    int oc = tid & 63;
    float invN = 1.0f / (float)N;
    float mu = stats[oc] * invN;
    float var = stats[HD + oc] * invN - mu * mu;
    float inv = rsqrtf(var + 1e-5f);
    y[tid] = g[oc] * (h[tid] - mu) * inv + be[oc];
}

// ---------------- pool[g] += y[n]; cnt[g] += 1 ----------------
__global__ void pool_kernel(const float* __restrict__ y, const int* __restrict__ batch,
                            float* __restrict__ pool, float* __restrict__ cnt, int N) {
    int tid = blockIdx.x * blockDim.x + threadIdx.x;
    int n = tid >> 6;
    int oc = tid & 63;
    if (n >= N) return;
    int gid = batch[n];
    unsafeAtomicAdd(&pool[(size_t)gid * HD + oc], y[(size_t)n * HD + oc]);
    if (oc == 0) unsafeAtomicAdd(&cnt[gid], 1.0f);
}

// ---------------- readout: out[g] = relu(mean @ Wf1 + bf1) @ Wf2 + bf2 ----------------
__global__ void readout_kernel(const float* __restrict__ pool, const float* __restrict__ cnt,
                               const float* __restrict__ Wf1, const float* __restrict__ bf1,
                               const float* __restrict__ Wf2, const float* __restrict__ bf2,
                               float* __restrict__ out) {
    int g = blockIdx.x;
    int t = threadIdx.x;  // 64 threads
    float c = fmaxf(cnt[g], 1.0f);
    float p = pool[(size_t)g * HD + t] / c;
    float o = 0.0f;
#pragma unroll
    for (int j = 0; j < 10; j++) {
        float part = p * Wf1[t * 10 + j];
#pragma unroll
        for (int off = 32; off > 0; off >>= 1) part += __shfl_down(part, off);
        float z = fmaxf(part + bf1[j], 0.0f);   // valid on lane 0 only
        o = fmaf(z, Wf2[j], o);
    }
    if (t == 0) out[g] = o + bf2[0];
}

extern "C" void kernel_launch(void* const* d_in, const int* in_sizes, int n_in,
                              void* d_out, int out_size, void* d_ws, size_t ws_size,
                              hipStream_t stream) {
    const float* x      = (const float*)d_in[0];
    const int*   ei     = (const int*)d_in[1];
    const int*   batch  = (const int*)d_in[2];
    const float* W1a = (const float*)d_in[3];  const float* b1a = (const float*)d_in[4];
    const float* W1b = (const float*)d_in[5];  const float* b1b = (const float*)d_in[6];
    const float* e1  = (const float*)d_in[7];  const float* g1  = (const float*)d_in[8];
    const float* be1 = (const float*)d_in[9];
    const float* W2a = (const float*)d_in[10]; const float* b2a = (const float*)d_in[11];
    const float* W2b = (const float*)d_in[12]; const float* b2b = (const float*)d_in[13];
    const float* e2  = (const float*)d_in[14]; const float* g2  = (const float*)d_in[15];
    const float* be2 = (const float*)d_in[16];
    const float* W3a = (const float*)d_in[17]; const float* b3a = (const float*)d_in[18];
    const float* W3b = (const float*)d_in[19]; const float* b3b = (const float*)d_in[20];
    const float* e3  = (const float*)d_in[21]; const float* g3  = (const float*)d_in[22];
    const float* be3 = (const float*)d_in[23];
    const float* Wf1 = (const float*)d_in[24]; const float* bf1 = (const float*)d_in[25];
    const float* Wf2 = (const float*)d_in[26]; const float* bf2 = (const float*)d_in[27];

    const int N = in_sizes[2];        // batch has N entries
    const int E = in_sizes[1] / 2;
    const int G = out_size;           // [G,1] output

    // workspace layout (floats)
    float* ws = (float*)d_ws;
    size_t NH = (size_t)N * HD;
    float* aggr  = ws;            // N*64
    float* tbuf  = aggr + NH;     // N*64
    float* hA    = tbuf + NH;     // N*64
    float* hB    = hA + NH;       // N*64
    float* stats = hB + NH;       // 128
    float* pool  = stats + 2 * HD;    // G*64
    float* cnt   = pool + (size_t)G * HD;  // G

    const int TB = 256;
    int gridNH = (int)((NH + TB - 1) / TB);

    // ---- one GIN layer ----
    auto layer = [&](const float* xin, int din, int shift,
                     const float* Wa, const float* ba, const float* Wb, const float* bb,
                     const float* eps, const float* gg, const float* bbeta, float* yout) {
        hipMemsetAsync(aggr, 0, (size_t)N * din * sizeof(float), stream);
        int total = E << shift;
        scatter_kernel<<<(total + TB - 1) / TB, TB, 0, stream>>>(xin, ei, aggr, E, din, shift);
        if (din == 16)
            lin_a_kernel<16><<<gridNH, TB, 0, stream>>>(xin, aggr, Wa, ba, eps, tbuf, N);
        else
            lin_a_kernel<64><<<gridNH, TB, 0, stream>>>(xin, aggr, Wa, ba, eps, tbuf, N);
        hipMemsetAsync(stats, 0, 2 * HD * sizeof(float), stream);
        lin_b_stats_kernel<<<(N + 31) / 32, TB, 0, stream>>>(tbuf, Wb, bb, hA == yout ? hB : hA, stats, N);
        // note: we want pre-BN h in a scratch distinct from yout; use tbuf? tbuf free now.
        // Simpler: we wrote h into (hA==yout? hB : hA); normalize from there into yout.
        const float* hsrc = (hA == yout) ? hB : hA;
        bn_kernel<<<gridNH, TB, 0, stream>>>(hsrc, stats, gg, bbeta, yout, N);
    };

    // layer1: x[N,16] -> hA ; layer2: hA -> hB ; layer3: hB -> hA
    layer(x,  16, 2, W1a, b1a, W1b, b1b, e1, g1, be1, hA);
    layer(hA, 64, 4, W2a, b2a, W2b, b2b, e2, g2, be2, hB);
    layer(hB, 64, 4, W3a, b3a, W3b, b3b, e3, g3, be3, hA);

    // ---- global mean pool + readout ----
    hipMemsetAsync(pool, 0, ((size_t)G * HD + G) * sizeof(float), stream);
    pool_kernel<<<gridNH, TB, 0, stream>>>(hA, batch, pool, cnt, N);
    readout_kernel<<<G, 64, 0, stream>>>(pool, cnt, Wf1, bf1, Wf2, bf2, (float*)d_out);
}

// Round 2
// 1177.266 us; speedup vs baseline: 2.6851x; 2.6851x over previous
//
#include <hip/hip_runtime.h>
#include <hip/hip_bf16.h>

// GIN net: 3x { CSR gather aggr; h=(1+eps)x+aggr; Lin+ReLU; Lin+ReLU; BN(train) }
// then mean-pool per graph + 2-layer readout MLP.
// N=100000 nodes, E=1200000 edges, F_IN=16, H=64, G=1024.
// Round 1 -> 2: replaced atomic scatter (3x1020us, atomic-bound) with per-call
// CSR-by-dst build (int atomics only) + wave-per-node gather aggregation.

#define HD 64

// ================= CSR build =================
__global__ void degree_kernel(const int* __restrict__ ei, int* __restrict__ deg, int E) {
    int e = blockIdx.x * blockDim.x + threadIdx.x;
    if (e >= E) return;
    atomicAdd(&deg[ei[E + e]], 1);
}

// block partial sums over chunks of 1024 (256 thr x 4)
__global__ void blocksum_kernel(const int* __restrict__ deg, int* __restrict__ bsum, int N) {
    __shared__ int wsum[4];
    int base = blockIdx.x * 1024 + threadIdx.x * 4;
    int s = 0;
#pragma unroll
    for (int k = 0; k < 4; k++) { int i = base + k; if (i < N) s += deg[i]; }
    // wave reduce
    for (int off = 1; off < 64; off <<= 1) s += __shfl_xor(s, off);
    if ((threadIdx.x & 63) == 0) wsum[threadIdx.x >> 6] = s;
    __syncthreads();
    if (threadIdx.x == 0) bsum[blockIdx.x] = wsum[0] + wsum[1] + wsum[2] + wsum[3];
}

// single-thread scan of block sums (nb ~ 98)
__global__ void scansums_kernel(const int* __restrict__ bsum, int* __restrict__ boff, int nb) {
    if (threadIdx.x != 0 || blockIdx.x != 0) return;
    int acc = 0;
    for (int i = 0; i < nb; i++) { boff[i] = acc; acc += bsum[i]; }
}

// write row_start[i+1] = exclusive_scan(deg)[i] + deg[i] (i.e. inclusive), row_start[0]=0
__global__ void scanwrite_kernel(const int* __restrict__ deg, const int* __restrict__ boff,
                                 int* __restrict__ row_start, int N) {
    __shared__ int wsumS[4];
    int lane = threadIdx.x & 63, wid = threadIdx.x >> 6;
    int base = blockIdx.x * 1024 + threadIdx.x * 4;
    int v0 = 0, v1 = 0, v2 = 0, v3 = 0;
    if (base + 0 < N) v0 = deg[base + 0];
    if (base + 1 < N) v1 = deg[base + 1];
    if (base + 2 < N) v2 = deg[base + 2];
    if (base + 3 < N) v3 = deg[base + 3];
    int st = v0 + v1 + v2 + v3;
    // inclusive wave scan of st
    int v = st;
    for (int off = 1; off < 64; off <<= 1) { int u = __shfl_up(v, off); if (lane >= off) v += u; }
    if (lane == 63) wsumS[wid] = v;
    __syncthreads();
    int woff = 0;
    for (int w = 0; w < wid; w++) woff += wsumS[w];
    int excl = boff[blockIdx.x] + woff + (v - st);   // exclusive prefix for this thread's 4 elems
    if (blockIdx.x == 0 && threadIdx.x == 0) row_start[0] = 0;
    int r = excl;
    if (base + 0 < N) { r += v0; row_start[base + 1] = r; }
    if (base + 1 < N) { r += v1; row_start[base + 2] = r; }
    if (base + 2 < N) { r += v2; row_start[base + 3] = r; }
    if (base + 3 < N) { r += v3; row_start[base + 4] = r; }
}

__global__ void fill_kernel(const int* __restrict__ ei, const int* __restrict__ row_start,
                            int* __restrict__ cursor, int* __restrict__ csr, int E) {
    int e = blockIdx.x * blockDim.x + threadIdx.x;
    if (e >= E) return;
    int dst = ei[E + e];
    int pos = atomicAdd(&cursor[dst], 1);
    csr[row_start[dst] + pos] = ei[e];
}

// ================= gather aggregation =================
// d=64: one wave per node, lane = channel
__global__ void gather64_kernel(const float* __restrict__ x, const int* __restrict__ rs,
                                const int* __restrict__ csr, float* __restrict__ aggr, int N) {
    int lane = threadIdx.x & 63;
    int n = blockIdx.x * (blockDim.x >> 6) + (threadIdx.x >> 6);
    if (n >= N) return;
    int beg = rs[n], end = rs[n + 1];
    float acc = 0.0f;
    for (int base = beg; base < end; base += 64) {
        int cnt = end - base; if (cnt > 64) cnt = 64;
        int e = (lane < cnt) ? csr[base + lane] : 0;
        for (int j = 0; j < cnt; j++) {
            int s = __shfl(e, j);
            acc += x[(size_t)s * 64 + lane];
        }
    }
    aggr[(size_t)n * 64 + lane] = acc;
}

// d=16: 16-lane group per node
__global__ void gather16_kernel(const float* __restrict__ x, const int* __restrict__ rs,
                                const int* __restrict__ csr, float* __restrict__ aggr, int N) {
    int lane = threadIdx.x & 15;
    int n = blockIdx.x * (blockDim.x >> 4) + (threadIdx.x >> 4);
    if (n >= N) return;
    int beg = rs[n], end = rs[n + 1];
    float acc = 0.0f;
    for (int base = beg; base < end; base += 16) {
        int cnt = end - base; if (cnt > 16) cnt = 16;
        int e = (lane < cnt) ? csr[base + lane] : 0;
        for (int j = 0; j < cnt; j++) {
            int s = __shfl(e, j, 16);
            acc += x[(size_t)s * 16 + lane];
        }
    }
    aggr[(size_t)n * 16 + lane] = acc;
}

// ================= t = relu( ((1+eps)*x + aggr) @ Wa + ba ) =================
template <int DIN>
__global__ void lin_a_kernel(const float* __restrict__ xin, const float* __restrict__ aggr,
                             const float* __restrict__ W, const float* __restrict__ b,
                             const float* __restrict__ epsp,
                             float* __restrict__ out, int N) {
    __shared__ float Ws[DIN * HD];
    for (int i = threadIdx.x; i < DIN * HD; i += blockDim.x) Ws[i] = W[i];
    __syncthreads();
    int tid = blockIdx.x * blockDim.x + threadIdx.x;
    int n = tid >> 6;
    int oc = tid & 63;
    if (n >= N) return;
    float e1 = 1.0f + epsp[0];
    float acc = b[oc];
    const float* xr = xin + (size_t)n * DIN;
    const float* ar = aggr + (size_t)n * DIN;
#pragma unroll
    for (int k = 0; k < DIN; k++) {
        float h = e1 * xr[k] + ar[k];
        acc = fmaf(h, Ws[k * HD + oc], acc);
    }
    out[(size_t)n * HD + oc] = fmaxf(acc, 0.0f);
}

// ============ h = relu( t @ Wb + bb ); per-channel sum/sumsq ============
__global__ void lin_b_stats_kernel(const float* __restrict__ t,
                                   const float* __restrict__ W, const float* __restrict__ b,
                                   float* __restrict__ h, float* __restrict__ stats, int N) {
    __shared__ float Ws[HD * HD];
    __shared__ float red[2][4][HD];
    for (int i = threadIdx.x; i < HD * HD; i += blockDim.x) Ws[i] = W[i];
    __syncthreads();
    const int ROWS = 32;
    int oc = threadIdx.x & 63;
    int slot = threadIdx.x >> 6;   // 0..3
    int base = blockIdx.x * ROWS;
    float s = 0.0f, s2 = 0.0f;
    for (int r = slot; r < ROWS; r += 4) {
        int n = base + r;
        if (n >= N) break;
        float acc = b[oc];
        const float* tr = t + (size_t)n * HD;
#pragma unroll 16
        for (int k = 0; k < HD; k++) acc = fmaf(tr[k], Ws[k * HD + oc], acc);
        acc = fmaxf(acc, 0.0f);
        h[(size_t)n * HD + oc] = acc;
        s += acc;
        s2 += acc * acc;
    }
    red[0][slot][oc] = s;
    red[1][slot][oc] = s2;
    __syncthreads();
    if (slot == 0) {
        float ts  = red[0][0][oc] + red[0][1][oc] + red[0][2][oc] + red[0][3][oc];
        float ts2 = red[1][0][oc] + red[1][1][oc] + red[1][2][oc] + red[1][3][oc];
        unsafeAtomicAdd(&stats[oc], ts);
        unsafeAtomicAdd(&stats[HD + oc], ts2);
    }
}

// ================= y = g*(h-mu)*rsqrt(var+eps)+be =================
__global__ void bn_kernel(const float* __restrict__ h, const float* __restrict__ stats,
                          const float* __restrict__ g, const float* __restrict__ be,
                          float* __restrict__ y, int N) {
    int tid = blockIdx.x * blockDim.x + threadIdx.x;
    if (tid >= N * HD) return;
    int oc = tid & 63;
    float invN = 1.0f / (float)N;
    float mu = stats[oc] * invN;
    float var = stats[HD + oc] * invN - mu * mu;
    float inv = rsqrtf(var + 1e-5f);
    y[tid] = g[oc] * (h[tid] - mu) * inv + be[oc];
}

// ================= pool[g] += y[n]; cnt[g] += 1 =================
__global__ void pool_kernel(const float* __restrict__ y, const int* __restrict__ batch,
                            float* __restrict__ pool, float* __restrict__ cnt, int N) {
    int tid = blockIdx.x * blockDim.x + threadIdx.x;
    int n = tid >> 6;
    int oc = tid & 63;
    if (n >= N) return;
    int gid = batch[n];
    unsafeAtomicAdd(&pool[(size_t)gid * HD + oc], y[(size_t)n * HD + oc]);
    if (oc == 0) unsafeAtomicAdd(&cnt[gid], 1.0f);
}

// ================= readout =================
__global__ void readout_kernel(const float* __restrict__ pool, const float* __restrict__ cnt,
                               const float* __restrict__ Wf1, const float* __restrict__ bf1,
                               const float* __restrict__ Wf2, const float* __restrict__ bf2,
                               float* __restrict__ out) {
    int g = blockIdx.x;
    int t = threadIdx.x;  // 64 threads
    float c = fmaxf(cnt[g], 1.0f);
    float p = pool[(size_t)g * HD + t] / c;
    float o = 0.0f;
#pragma unroll
    for (int j = 0; j < 10; j++) {
        float part = p * Wf1[t * 10 + j];
#pragma unroll
        for (int off = 32; off > 0; off >>= 1) part += __shfl_down(part, off);
        float z = fmaxf(part + bf1[j], 0.0f);   // valid on lane 0 only
        o = fmaf(z, Wf2[j], o);
    }
    if (t == 0) out[g] = o + bf2[0];
}

extern "C" void kernel_launch(void* const* d_in, const int* in_sizes, int n_in,
                              void* d_out, int out_size, void* d_ws, size_t ws_size,
                              hipStream_t stream) {
    const float* x      = (const float*)d_in[0];
    const int*   ei     = (const int*)d_in[1];
    const int*   batch  = (const int*)d_in[2];
    const float* W1a = (const float*)d_in[3];  const float* b1a = (const float*)d_in[4];
    const float* W1b = (const float*)d_in[5];  const float* b1b = (const float*)d_in[6];
    const float* e1  = (const float*)d_in[7];  const float* g1  = (const float*)d_in[8];
    const float* be1 = (const float*)d_in[9];
    const float* W2a = (const float*)d_in[10]; const float* b2a = (const float*)d_in[11];
    const float* W2b = (const float*)d_in[12]; const float* b2b = (const float*)d_in[13];
    const float* e2  = (const float*)d_in[14]; const float* g2  = (const float*)d_in[15];
    const float* be2 = (const float*)d_in[16];
    const float* W3a = (const float*)d_in[17]; const float* b3a = (const float*)d_in[18];
    const float* W3b = (const float*)d_in[19]; const float* b3b = (const float*)d_in[20];
    const float* e3  = (const float*)d_in[21]; const float* g3  = (const float*)d_in[22];
    const float* be3 = (const float*)d_in[23];
    const float* Wf1 = (const float*)d_in[24]; const float* bf1 = (const float*)d_in[25];
    const float* Wf2 = (const float*)d_in[26]; const float* bf2 = (const float*)d_in[27];

    const int N = in_sizes[2];
    const int E = in_sizes[1] / 2;
    const int G = out_size;

    // ---------- workspace layout ----------
    // ints first
    int* csr       = (int*)d_ws;                 // E
    int* row_start = csr + E;                    // N+1 (pad to +64)
    int* deg       = row_start + N + 64;         // N
    int* cursor    = deg + N;                    // N
    int* bsum      = cursor + N;                 // 256
    int* boff      = bsum + 256;                 // 256
    float* fbase   = (float*)(boff + 256);
    size_t NH = (size_t)N * HD;
    float* aggr  = fbase;                        // N*64
    float* tbuf  = aggr + NH;                    // N*64
    float* hA    = tbuf + NH;                    // N*64
    float* hB    = hA + NH;                      // N*64
    float* stats = hB + NH;                      // 128
    float* pool  = stats + 2 * HD;               // G*64
    float* cnt   = pool + (size_t)G * HD;        // G

    const int TB = 256;
    int gridNH = (int)((NH + TB - 1) / TB);
    int nb = (N + 1023) / 1024;

    // ---------- CSR build (per call; ws is re-poisoned every launch) ----------
    hipMemsetAsync(deg, 0, 2 * (size_t)N * sizeof(int), stream);   // deg + cursor
    degree_kernel<<<(E + TB - 1) / TB, TB, 0, stream>>>(ei, deg, E);
    blocksum_kernel<<<nb, TB, 0, stream>>>(deg, bsum, N);
    scansums_kernel<<<1, 64, 0, stream>>>(bsum, boff, nb);
    scanwrite_kernel<<<nb, TB, 0, stream>>>(deg, boff, row_start, N);
    fill_kernel<<<(E + TB - 1) / TB, TB, 0, stream>>>(ei, row_start, cursor, csr, E);

    // ---------- one GIN layer ----------
    auto layer = [&](const float* xin, int din,
                     const float* Wa, const float* ba, const float* Wb, const float* bb,
                     const float* eps, const float* gg, const float* bbeta, float* yout) {
        if (din == 16) {
            gather16_kernel<<<(N * 16 + TB - 1) / TB, TB, 0, stream>>>(xin, row_start, csr, aggr, N);
            lin_a_kernel<16><<<gridNH, TB, 0, stream>>>(xin, aggr, Wa, ba, eps, tbuf, N);
        } else {
            gather64_kernel<<<(N * 64 + TB - 1) / TB, TB, 0, stream>>>(xin, row_start, csr, aggr, N);
            lin_a_kernel<64><<<gridNH, TB, 0, stream>>>(xin, aggr, Wa, ba, eps, tbuf, N);
        }
        hipMemsetAsync(stats, 0, 2 * HD * sizeof(float), stream);
        float* hsrc = (hA == yout) ? hB : hA;
        lin_b_stats_kernel<<<(N + 31) / 32, TB, 0, stream>>>(tbuf, Wb, bb, hsrc, stats, N);
        bn_kernel<<<gridNH, TB, 0, stream>>>(hsrc, stats, gg, bbeta, yout, N);
    };

    layer(x,  16, W1a, b1a, W1b, b1b, e1, g1, be1, hA);
    layer(hA, 64, W2a, b2a, W2b, b2b, e2, g2, be2, hB);
    layer(hB, 64, W3a, b3a, W3b, b3b, e3, g3, be3, hA);

    // ---------- global mean pool + readout ----------
    hipMemsetAsync(pool, 0, ((size_t)G * HD + G) * sizeof(float), stream);
    pool_kernel<<<gridNH, TB, 0, stream>>>(hA, batch, pool, cnt, N);
    readout_kernel<<<G, 64, 0, stream>>>(pool, cnt, Wf1, bf1, Wf2, bf2, (float*)d_out);
}

// Round 3
// 677.228 us; speedup vs baseline: 4.6676x; 1.7384x over previous
//
#include <hip/hip_runtime.h>
#include <hip/hip_bf16.h>

// GIN net, round 3: CSR gather + fused (LinA+ReLU+LinB+ReLU+stats) kernel,
// BN folded as per-channel affine into the NEXT layer's LinA (Wa_eff = diag(a)Wa,
// deg-dependent bias (1+eps+deg)*(c@Wa)), last BN folded into readout.
// Segmented (sorted-batch) pooling replaces contended atomics.

#define HD 64

// ================= CSR build =================
__global__ void degree_kernel(const int* __restrict__ ei, int* __restrict__ deg, int E) {
    int e = blockIdx.x * blockDim.x + threadIdx.x;
    if (e >= E) return;
    atomicAdd(&deg[ei[E + e]], 1);
}

__global__ void blocksum_kernel(const int* __restrict__ deg, int* __restrict__ bsum, int N) {
    __shared__ int wsum[4];
    int base = blockIdx.x * 1024 + threadIdx.x * 4;
    int s = 0;
#pragma unroll
    for (int k = 0; k < 4; k++) { int i = base + k; if (i < N) s += deg[i]; }
    for (int off = 1; off < 64; off <<= 1) s += __shfl_xor(s, off);
    if ((threadIdx.x & 63) == 0) wsum[threadIdx.x >> 6] = s;
    __syncthreads();
    if (threadIdx.x == 0) bsum[blockIdx.x] = wsum[0] + wsum[1] + wsum[2] + wsum[3];
}

__global__ void scansums_kernel(const int* __restrict__ bsum, int* __restrict__ boff, int nb) {
    if (threadIdx.x != 0 || blockIdx.x != 0) return;
    int acc = 0;
    for (int i = 0; i < nb; i++) { boff[i] = acc; acc += bsum[i]; }
}

__global__ void scanwrite_kernel(const int* __restrict__ deg, const int* __restrict__ boff,
                                 int* __restrict__ row_start, int N) {
    __shared__ int wsumS[4];
    int lane = threadIdx.x & 63, wid = threadIdx.x >> 6;
    int base = blockIdx.x * 1024 + threadIdx.x * 4;
    int v0 = 0, v1 = 0, v2 = 0, v3 = 0;
    if (base + 0 < N) v0 = deg[base + 0];
    if (base + 1 < N) v1 = deg[base + 1];
    if (base + 2 < N) v2 = deg[base + 2];
    if (base + 3 < N) v3 = deg[base + 3];
    int st = v0 + v1 + v2 + v3;
    int v = st;
    for (int off = 1; off < 64; off <<= 1) { int u = __shfl_up(v, off); if (lane >= off) v += u; }
    if (lane == 63) wsumS[wid] = v;
    __syncthreads();
    int woff = 0;
    for (int w = 0; w < wid; w++) woff += wsumS[w];
    int excl = boff[blockIdx.x] + woff + (v - st);
    if (blockIdx.x == 0 && threadIdx.x == 0) row_start[0] = 0;
    int r = excl;
    if (base + 0 < N) { r += v0; row_start[base + 1] = r; }
    if (base + 1 < N) { r += v1; row_start[base + 2] = r; }
    if (base + 2 < N) { r += v2; row_start[base + 3] = r; }
    if (base + 3 < N) { r += v3; row_start[base + 4] = r; }
}

__global__ void fill_kernel(const int* __restrict__ ei, const int* __restrict__ row_start,
                            int* __restrict__ cursor, int* __restrict__ csr, int E) {
    int e = blockIdx.x * blockDim.x + threadIdx.x;
    if (e >= E) return;
    int dst = ei[E + e];
    int pos = atomicAdd(&cursor[dst], 1);
    csr[row_start[dst] + pos] = ei[e];
}

// ================= gather aggregation (raw features, BN folded downstream) ==========
__global__ void gather64_kernel(const float* __restrict__ x, const int* __restrict__ rs,
                                const int* __restrict__ csr, float* __restrict__ aggr, int N) {
    int lane = threadIdx.x & 63;
    int n = blockIdx.x * (blockDim.x >> 6) + (threadIdx.x >> 6);
    if (n >= N) return;
    int beg = rs[n], end = rs[n + 1];
    float acc = 0.0f;
    for (int base = beg; base < end; base += 64) {
        int cnt = end - base; if (cnt > 64) cnt = 64;
        int e = (lane < cnt) ? csr[base + lane] : 0;
        for (int j = 0; j < cnt; j++) {
            int s = __shfl(e, j);
            acc += x[(size_t)s * 64 + lane];
        }
    }
    aggr[(size_t)n * 64 + lane] = acc;
}

__global__ void gather16_kernel(const float* __restrict__ x, const int* __restrict__ rs,
                                const int* __restrict__ csr, float* __restrict__ aggr, int N) {
    int lane = threadIdx.x & 15;
    int n = blockIdx.x * (blockDim.x >> 4) + (threadIdx.x >> 4);
    if (n >= N) return;
    int beg = rs[n], end = rs[n + 1];
    float acc = 0.0f;
    for (int base = beg; base < end; base += 16) {
        int cnt = end - base; if (cnt > 16) cnt = 16;
        int e = (lane < cnt) ? csr[base + lane] : 0;
        for (int j = 0; j < cnt; j++) {
            int s = __shfl(e, j, 16);
            acc += x[(size_t)s * 16 + lane];
        }
    }
    aggr[(size_t)n * 16 + lane] = acc;
}

// ================= prep: fold previous BN into this layer's Wa =================
// a = g*rsqrt(var+eps), c = be - mu*a ; WaEff[k][oc] = a[k]*Wa[k][oc] ; u = c @ Wa
__global__ void prep_kernel(const float* __restrict__ stats, const float* __restrict__ g,
                            const float* __restrict__ be, const float* __restrict__ Wa,
                            float* __restrict__ WaEff, float* __restrict__ u, int N) {
    __shared__ float aS[64], cS[64];
    int tid = threadIdx.x;
    if (tid < 64) {
        float invN = 1.0f / (float)N;
        float mu = stats[tid] * invN;
        float var = stats[64 + tid] * invN - mu * mu;
        float inv = rsqrtf(var + 1e-5f);
        float a = g[tid] * inv;
        aS[tid] = a;
        cS[tid] = be[tid] - mu * a;
    }
    __syncthreads();
    for (int i = tid; i < 4096; i += 256) WaEff[i] = aS[i >> 6] * Wa[i];
    if (tid < 64) {
        float s = 0.0f;
        for (int k = 0; k < 64; k++) s = fmaf(cS[k], Wa[k * 64 + tid], s);
        u[tid] = s;
    }
}

// ================= fused: t=relu(z@Wa+bias(deg)); h=relu(t@Wb+bb); stats =================
// z = (1+eps)*xin + aggr (raw); AFF folds prev BN: Wa is WaEff, bias += (1+eps+deg)*u
template <int DIN, bool AFF>
__launch_bounds__(256)
__global__ void fused_mlp_kernel(const float* __restrict__ xin, const float* __restrict__ aggr,
                                 const int* __restrict__ rs,
                                 const float* __restrict__ Wa, const float* __restrict__ ba,
                                 const float* __restrict__ u,
                                 const float* __restrict__ Wb, const float* __restrict__ bb,
                                 const float* __restrict__ epsp,
                                 float* __restrict__ hout, float* __restrict__ stats, int N) {
    __shared__ float Wa_s[DIN * 64];
    __shared__ float Wb_s[64 * 64];
    __shared__ float zs[16 * DIN];
    __shared__ float ts[16 * 64];
    __shared__ float statS[128];
    __shared__ float degS[16];

    int tid = threadIdx.x;
    for (int i = tid; i < DIN * 64; i += 256) Wa_s[i] = Wa[i];
    for (int i = tid; i < 64 * 64; i += 256) Wb_s[i] = Wb[i];
    if (tid < 128) statS[tid] = 0.0f;
    float e1 = 1.0f + epsp[0];

    int nn = tid >> 4;            // node slot 0..15
    int ocg = (tid & 15) * 4;     // channel group
    float4 ba4 = *(const float4*)&ba[ocg];
    float4 bb4 = *(const float4*)&bb[ocg];
    float4 u4 = {0, 0, 0, 0};
    if (AFF) u4 = *(const float4*)&u[ocg];

    float s0 = 0, s1 = 0, s2 = 0, s3 = 0, q0 = 0, q1 = 0, q2 = 0, q3 = 0;

    const int ITER = 8;
    int blockBase = blockIdx.x * (16 * ITER);
    for (int it = 0; it < ITER; it++) {
        int gbase = blockBase + it * 16;
        // ---- Phase A: z tile -> LDS ----
        if (DIN == 64) {
            int idx = tid * 4;
            int nl = idx >> 6, ch = idx & 63;
            int node = gbase + nl;
            float4 z4 = {0, 0, 0, 0};
            if (node < N) {
                float4 xv = *(const float4*)&xin[(size_t)node * 64 + ch];
                float4 av = *(const float4*)&aggr[(size_t)node * 64 + ch];
                z4.x = fmaf(e1, xv.x, av.x);
                z4.y = fmaf(e1, xv.y, av.y);
                z4.z = fmaf(e1, xv.z, av.z);
                z4.w = fmaf(e1, xv.w, av.w);
            }
            *(float4*)&zs[nl * 64 + ch] = z4;
        } else {
            if (tid < 64) {
                int idx = tid * 4;
                int nl = idx >> 4, ch = idx & 15;
                int node = gbase + nl;
                float4 z4 = {0, 0, 0, 0};
                if (node < N) {
                    float4 xv = *(const float4*)&xin[(size_t)node * 16 + ch];
                    float4 av = *(const float4*)&aggr[(size_t)node * 16 + ch];
                    z4.x = fmaf(e1, xv.x, av.x);
                    z4.y = fmaf(e1, xv.y, av.y);
                    z4.z = fmaf(e1, xv.z, av.z);
                    z4.w = fmaf(e1, xv.w, av.w);
                }
                *(float4*)&zs[nl * 16 + ch] = z4;
            }
        }
        if (AFF && tid < 16) {
            int node = gbase + tid;
            degS[tid] = (node < N) ? (float)(rs[node + 1] - rs[node]) : 0.0f;
        }
        __syncthreads();
        // ---- Phase B: t = relu(z @ Wa + bias) ----
        float4 acc = ba4;
        if (AFF) {
            float f = e1 + degS[nn];
            acc.x = fmaf(f, u4.x, acc.x);
            acc.y = fmaf(f, u4.y, acc.y);
            acc.z = fmaf(f, u4.z, acc.z);
            acc.w = fmaf(f, u4.w, acc.w);
        }
#pragma unroll
        for (int k = 0; k < DIN; k++) {
            float s = zs[nn * DIN + k];
            float4 w = *(const float4*)&Wa_s[k * 64 + ocg];
            acc.x = fmaf(s, w.x, acc.x);
            acc.y = fmaf(s, w.y, acc.y);
            acc.z = fmaf(s, w.z, acc.z);
            acc.w = fmaf(s, w.w, acc.w);
        }
        acc.x = fmaxf(acc.x, 0.0f); acc.y = fmaxf(acc.y, 0.0f);
        acc.z = fmaxf(acc.z, 0.0f); acc.w = fmaxf(acc.w, 0.0f);
        *(float4*)&ts[nn * 64 + ocg] = acc;
        __syncthreads();
        // ---- Phase C: h = relu(t @ Wb + bb), store + stats ----
        float4 hc = bb4;
#pragma unroll
        for (int k = 0; k < 64; k++) {
            float s = ts[nn * 64 + k];
            float4 w = *(const float4*)&Wb_s[k * 64 + ocg];
            hc.x = fmaf(s, w.x, hc.x);
            hc.y = fmaf(s, w.y, hc.y);
            hc.z = fmaf(s, w.z, hc.z);
            hc.w = fmaf(s, w.w, hc.w);
        }
        hc.x = fmaxf(hc.x, 0.0f); hc.y = fmaxf(hc.y, 0.0f);
        hc.z = fmaxf(hc.z, 0.0f); hc.w = fmaxf(hc.w, 0.0f);
        int node = gbase + nn;
        if (node < N) {
            *(float4*)&hout[(size_t)node * 64 + ocg] = hc;
            s0 += hc.x; s1 += hc.y; s2 += hc.z; s3 += hc.w;
            q0 += hc.x * hc.x; q1 += hc.y * hc.y; q2 += hc.z * hc.z; q3 += hc.w * hc.w;
        }
    }
    __syncthreads();
    atomicAdd(&statS[ocg + 0], s0);
    atomicAdd(&statS[ocg + 1], s1);
    atomicAdd(&statS[ocg + 2], s2);
    atomicAdd(&statS[ocg + 3], s3);
    atomicAdd(&statS[64 + ocg + 0], q0);
    atomicAdd(&statS[64 + ocg + 1], q1);
    atomicAdd(&statS[64 + ocg + 2], q2);
    atomicAdd(&statS[64 + ocg + 3], q3);
    __syncthreads();
    if (tid < 128) unsafeAtomicAdd(&stats[tid], statS[tid]);
}

// ================= segmented pool (batch sorted): flush on gid change =================
__global__ void pool_seg_kernel(const float* __restrict__ h, const int* __restrict__ batch,
                                float* __restrict__ pool, float* __restrict__ cnt, int N) {
    int lane = threadIdx.x & 63;
    int wave = (blockIdx.x * blockDim.x + threadIdx.x) >> 6;
    int base = wave * 16;
    if (base >= N) return;
    int end = base + 16; if (end > N) end = N;
    int cur = batch[base];
    float acc = 0.0f;
    int run = 0;
    for (int n = base; n < end; n++) {
        int gid = batch[n];
        if (gid != cur) {
            unsafeAtomicAdd(&pool[(size_t)cur * 64 + lane], acc);
            if (lane == 0) unsafeAtomicAdd(&cnt[cur], (float)run);
            acc = 0.0f; run = 0; cur = gid;
        }
        acc += h[(size_t)n * 64 + lane];
        run++;
    }
    unsafeAtomicAdd(&pool[(size_t)cur * 64 + lane], acc);
    if (lane == 0) unsafeAtomicAdd(&cnt[cur], (float)run);
}

// ================= readout: apply layer-3 BN affine to pooled mean, then MLP ==========
__global__ void readout_kernel(const float* __restrict__ pool, const float* __restrict__ cnt,
                               const float* __restrict__ stats, const float* __restrict__ g3,
                               const float* __restrict__ be3,
                               const float* __restrict__ Wf1, const float* __restrict__ bf1,
                               const float* __restrict__ Wf2, const float* __restrict__ bf2,
                               float* __restrict__ out, int N) {
    int gb = blockIdx.x;
    int t = threadIdx.x;  // 64 threads
    float invN = 1.0f / (float)N;
    float mu = stats[t] * invN;
    float var = stats[64 + t] * invN - mu * mu;
    float inv = rsqrtf(var + 1e-5f);
    float a = g3[t] * inv;
    float c = be3[t] - mu * a;
    float cn = cnt[gb];
    float p = (cn > 0.0f) ? (a * (pool[(size_t)gb * 64 + t] / cn) + c) : 0.0f;
    float o = 0.0f;
#pragma unroll
    for (int j = 0; j < 10; j++) {
        float part = p * Wf1[t * 10 + j];
#pragma unroll
        for (int off = 32; off > 0; off >>= 1) part += __shfl_down(part, off);
        float z = fmaxf(part + bf1[j], 0.0f);   // valid on lane 0 only
        o = fmaf(z, Wf2[j], o);
    }
    if (t == 0) out[gb] = o + bf2[0];
}

extern "C" void kernel_launch(void* const* d_in, const int* in_sizes, int n_in,
                              void* d_out, int out_size, void* d_ws, size_t ws_size,
                              hipStream_t stream) {
    const float* x      = (const float*)d_in[0];
    const int*   ei     = (const int*)d_in[1];
    const int*   batch  = (const int*)d_in[2];
    const float* W1a = (const float*)d_in[3];  const float* b1a = (const float*)d_in[4];
    const float* W1b = (const float*)d_in[5];  const float* b1b = (const float*)d_in[6];
    const float* e1  = (const float*)d_in[7];  const float* g1  = (const float*)d_in[8];
    const float* be1 = (const float*)d_in[9];
    const float* W2a = (const float*)d_in[10]; const float* b2a = (const float*)d_in[11];
    const float* W2b = (const float*)d_in[12]; const float* b2b = (const float*)d_in[13];
    const float* e2  = (const float*)d_in[14]; const float* g2  = (const float*)d_in[15];
    const float* be2 = (const float*)d_in[16];
    const float* W3a = (const float*)d_in[17]; const float* b3a = (const float*)d_in[18];
    const float* W3b = (const float*)d_in[19]; const float* b3b = (const float*)d_in[20];
    const float* e3  = (const float*)d_in[21]; const float* g3  = (const float*)d_in[22];
    const float* be3 = (const float*)d_in[23];
    const float* Wf1 = (const float*)d_in[24]; const float* bf1 = (const float*)d_in[25];
    const float* Wf2 = (const float*)d_in[26]; const float* bf2 = (const float*)d_in[27];

    const int N = in_sizes[2];
    const int E = in_sizes[1] / 2;
    const int G = out_size;

    // ---------- workspace layout ----------
    int* csr       = (int*)d_ws;                 // E
    int* row_start = csr + E;                    // N+1 (+pad)
    int* deg       = row_start + N + 64;         // N
    int* cursor    = deg + N;                    // N
    int* bsum      = cursor + N;                 // 256
    int* boff      = bsum + 256;                 // 256
    float* fbase   = (float*)(boff + 256);
    size_t NH = (size_t)N * HD;
    float* aggr   = fbase;                       // N*64
    float* hA     = aggr + NH;                   // N*64
    float* hB     = hA + NH;                     // N*64
    float* stats  = hB + NH;                     // 3*128
    float* WaEff2 = stats + 384;                 // 4096
    float* u2     = WaEff2 + 4096;               // 64
    float* WaEff3 = u2 + 64;                     // 4096
    float* u3     = WaEff3 + 4096;               // 64
    float* pool   = u3 + 64;                     // G*64
    float* cnt    = pool + (size_t)G * HD;       // G

    const int TB = 256;
    int nb = (N + 1023) / 1024;
    int fusedGrid = (N + 127) / 128;

    // ---------- CSR build ----------
    hipMemsetAsync(deg, 0, 2 * (size_t)N * sizeof(int), stream);   // deg + cursor
    hipMemsetAsync(stats, 0, 384 * sizeof(float), stream);
    hipMemsetAsync(pool, 0, ((size_t)G * HD + G) * sizeof(float), stream);
    degree_kernel<<<(E + TB - 1) / TB, TB, 0, stream>>>(ei, deg, E);
    blocksum_kernel<<<nb, TB, 0, stream>>>(deg, bsum, N);
    scansums_kernel<<<1, 64, 0, stream>>>(bsum, boff, nb);
    scanwrite_kernel<<<nb, TB, 0, stream>>>(deg, boff, row_start, N);
    fill_kernel<<<(E + TB - 1) / TB, TB, 0, stream>>>(ei, row_start, cursor, csr, E);

    // ---------- layer 1: x(16) -> hA (raw pre-BN h1), stats1 ----------
    gather16_kernel<<<(N * 16 + TB - 1) / TB, TB, 0, stream>>>(x, row_start, csr, aggr, N);
    fused_mlp_kernel<16, false><<<fusedGrid, TB, 0, stream>>>(
        x, aggr, row_start, W1a, b1a, nullptr, W1b, b1b, e1, hA, stats, N);

    // ---------- layer 2: hA(raw) -> hB, BN1 folded via WaEff2/u2 ----------
    prep_kernel<<<1, 256, 0, stream>>>(stats, g1, be1, W2a, WaEff2, u2, N);
    gather64_kernel<<<(N * 64 + TB - 1) / TB, TB, 0, stream>>>(hA, row_start, csr, aggr, N);
    fused_mlp_kernel<64, true><<<fusedGrid, TB, 0, stream>>>(
        hA, aggr, row_start, WaEff2, b2a, u2, W2b, b2b, e2, hB, stats + 128, N);

    // ---------- layer 3: hB(raw) -> hA, BN2 folded via WaEff3/u3 ----------
    prep_kernel<<<1, 256, 0, stream>>>(stats + 128, g2, be2, W3a, WaEff3, u3, N);
    gather64_kernel<<<(N * 64 + TB - 1) / TB, TB, 0, stream>>>(hB, row_start, csr, aggr, N);
    fused_mlp_kernel<64, true><<<fusedGrid, TB, 0, stream>>>(
        hB, aggr, row_start, WaEff3, b3a, u3, W3b, b3b, e3, hA, stats + 256, N);

    // ---------- pool raw h3 (BN3 affine applied in readout) ----------
    int poolWaves = (N + 15) / 16;
    pool_seg_kernel<<<(poolWaves * 64 + TB - 1) / TB, TB, 0, stream>>>(hA, batch, pool, cnt, N);
    readout_kernel<<<G, 64, 0, stream>>>(pool, cnt, stats + 256, g3, be3,
                                         Wf1, bf1, Wf2, bf2, (float*)d_out, N);
}

// Round 4
// 523.544 us; speedup vs baseline: 6.0378x; 1.2935x over previous
//
#include <hip/hip_runtime.h>
#include <hip/hip_bf16.h>

// GIN net, round 4: register-tiled (4 nodes x 4 ch per thread) fused MLP with
// k-major transposed LDS tiles (conflict-free b128 reads), vectorized multi-edge
// gather (16 lanes/node, float4). BN folded into next LinA / readout as before.

#define HD 64

// ================= CSR build =================
__global__ void degree_kernel(const int* __restrict__ ei, int* __restrict__ deg, int E) {
    int e = blockIdx.x * blockDim.x + threadIdx.x;
    if (e >= E) return;
    atomicAdd(&deg[ei[E + e]], 1);
}

__global__ void blocksum_kernel(const int* __restrict__ deg, int* __restrict__ bsum, int N) {
    __shared__ int wsum[4];
    int base = blockIdx.x * 1024 + threadIdx.x * 4;
    int s = 0;
#pragma unroll
    for (int k = 0; k < 4; k++) { int i = base + k; if (i < N) s += deg[i]; }
    for (int off = 1; off < 64; off <<= 1) s += __shfl_xor(s, off);
    if ((threadIdx.x & 63) == 0) wsum[threadIdx.x >> 6] = s;
    __syncthreads();
    if (threadIdx.x == 0) bsum[blockIdx.x] = wsum[0] + wsum[1] + wsum[2] + wsum[3];
}

__global__ void scansums_kernel(const int* __restrict__ bsum, int* __restrict__ boff, int nb) {
    if (threadIdx.x != 0 || blockIdx.x != 0) return;
    int acc = 0;
    for (int i = 0; i < nb; i++) { boff[i] = acc; acc += bsum[i]; }
}

__global__ void scanwrite_kernel(const int* __restrict__ deg, const int* __restrict__ boff,
                                 int* __restrict__ row_start, int N) {
    __shared__ int wsumS[4];
    int lane = threadIdx.x & 63, wid = threadIdx.x >> 6;
    int base = blockIdx.x * 1024 + threadIdx.x * 4;
    int v0 = 0, v1 = 0, v2 = 0, v3 = 0;
    if (base + 0 < N) v0 = deg[base + 0];
    if (base + 1 < N) v1 = deg[base + 1];
    if (base + 2 < N) v2 = deg[base + 2];
    if (base + 3 < N) v3 = deg[base + 3];
    int st = v0 + v1 + v2 + v3;
    int v = st;
    for (int off = 1; off < 64; off <<= 1) { int u = __shfl_up(v, off); if (lane >= off) v += u; }
    if (lane == 63) wsumS[wid] = v;
    __syncthreads();
    int woff = 0;
    for (int w = 0; w < wid; w++) woff += wsumS[w];
    int excl = boff[blockIdx.x] + woff + (v - st);
    if (blockIdx.x == 0 && threadIdx.x == 0) row_start[0] = 0;
    int r = excl;
    if (base + 0 < N) { r += v0; row_start[base + 1] = r; }
    if (base + 1 < N) { r += v1; row_start[base + 2] = r; }
    if (base + 2 < N) { r += v2; row_start[base + 3] = r; }
    if (base + 3 < N) { r += v3; row_start[base + 4] = r; }
}

__global__ void fill_kernel(const int* __restrict__ ei, const int* __restrict__ row_start,
                            int* __restrict__ cursor, int* __restrict__ csr, int E) {
    int e = blockIdx.x * blockDim.x + threadIdx.x;
    if (e >= E) return;
    int dst = ei[E + e];
    int pos = atomicAdd(&cursor[dst], 1);
    csr[row_start[dst] + pos] = ei[e];
}

// ================= gather: 16 lanes/node, float4/lane, 16 edges in flight ========
__global__ void gather64_kernel(const float* __restrict__ x, const int* __restrict__ rs,
                                const int* __restrict__ csr, float* __restrict__ aggr, int N) {
    int lane = threadIdx.x & 63;
    int l4 = lane & 15;                       // channel quad
    int wave = (blockIdx.x * blockDim.x + threadIdx.x) >> 6;
    int n = wave * 4 + (lane >> 4);
    if (n >= N) return;
    int beg = rs[n], end = rs[n + 1];
    float ax = 0, ay = 0, az = 0, aw = 0;
    for (int base = beg; base < end; base += 16) {
        int cnt = end - base; if (cnt > 16) cnt = 16;
        int e = (l4 < cnt) ? csr[base + l4] : 0;
        for (int j = 0; j < cnt; j++) {
            int s = __shfl(e, j, 16);
            const float4 v = *reinterpret_cast<const float4*>(x + (size_t)s * 64 + l4 * 4);
            ax += v.x; ay += v.y; az += v.z; aw += v.w;
        }
    }
    float4 o = {ax, ay, az, aw};
    *reinterpret_cast<float4*>(aggr + (size_t)n * 64 + l4 * 4) = o;
}

__global__ void gather16_kernel(const float* __restrict__ x, const int* __restrict__ rs,
                                const int* __restrict__ csr, float* __restrict__ aggr, int N) {
    int lane = threadIdx.x & 63;
    int l4 = lane & 3;                        // channel quad (16 ch = 4 quads)
    int wave = (blockIdx.x * blockDim.x + threadIdx.x) >> 6;
    int n = wave * 16 + (lane >> 2);
    if (n >= N) return;
    int beg = rs[n], end = rs[n + 1];
    float ax = 0, ay = 0, az = 0, aw = 0;
    for (int base = beg; base < end; base += 4) {
        int cnt = end - base; if (cnt > 4) cnt = 4;
        int e = (l4 < cnt) ? csr[base + l4] : 0;
        for (int j = 0; j < cnt; j++) {
            int s = __shfl(e, j, 4);
            const float4 v = *reinterpret_cast<const float4*>(x + (size_t)s * 16 + l4 * 4);
            ax += v.x; ay += v.y; az += v.z; aw += v.w;
        }
    }
    float4 o = {ax, ay, az, aw};
    *reinterpret_cast<float4*>(aggr + (size_t)n * 16 + l4 * 4) = o;
}

// ================= prep: fold previous BN into this layer's Wa =================
__global__ void prep_kernel(const float* __restrict__ stats, const float* __restrict__ g,
                            const float* __restrict__ be, const float* __restrict__ Wa,
                            float* __restrict__ WaEff, float* __restrict__ u, int N) {
    __shared__ float aS[64], cS[64];
    int tid = threadIdx.x;
    if (tid < 64) {
        float invN = 1.0f / (float)N;
        float mu = stats[tid] * invN;
        float var = stats[64 + tid] * invN - mu * mu;
        float inv = rsqrtf(var + 1e-5f);
        float a = g[tid] * inv;
        aS[tid] = a;
        cS[tid] = be[tid] - mu * a;
    }
    __syncthreads();
    for (int i = tid; i < 4096; i += 256) WaEff[i] = aS[i >> 6] * Wa[i];
    if (tid < 64) {
        float s = 0.0f;
        for (int k = 0; k < 64; k++) s = fmaf(cS[k], Wa[k * 64 + tid], s);
        u[tid] = s;
    }
}

// ======== fused MLP: 4x4 register tile, k-major LDS (pad 68), aliased z/t ========
// thread (tc=tid&15, tn=tid>>4): nodes gbase+4*tn+i, channels 4*tc+j
template <int DIN, bool AFF>
__launch_bounds__(256)
__global__ void fused_mlp_kernel(const float* __restrict__ xin, const float* __restrict__ aggr,
                                 const int* __restrict__ rs,
                                 const float* __restrict__ Wa, const float* __restrict__ ba,
                                 const float* __restrict__ u,
                                 const float* __restrict__ Wb, const float* __restrict__ bb,
                                 const float* __restrict__ epsp,
                                 float* __restrict__ hout, float* __restrict__ stats, int N) {
    __shared__ float Wa_s[DIN * 64];
    __shared__ float Wb_s[64 * 64];
    __shared__ float zts[64 * 68];     // z tile (DIN rows) aliased with t tile (64 rows)
    __shared__ float statS[128];
    __shared__ float degS[64];

    const int tid = threadIdx.x;
    const int tc = tid & 15;
    const int tn = tid >> 4;

    for (int i = tid; i < DIN * 64; i += 256) Wa_s[i] = Wa[i];
    for (int i = tid; i < 64 * 64; i += 256) Wb_s[i] = Wb[i];
    if (tid < 128) statS[tid] = 0.0f;
    const float e1 = 1.0f + epsp[0];

    float4 t4;
    t4 = *(const float4*)&ba[tc * 4];
    const float bav[4] = {t4.x, t4.y, t4.z, t4.w};
    t4 = *(const float4*)&bb[tc * 4];
    const float bbv[4] = {t4.x, t4.y, t4.z, t4.w};
    float uv[4] = {0, 0, 0, 0};
    if (AFF) { t4 = *(const float4*)&u[tc * 4]; uv[0] = t4.x; uv[1] = t4.y; uv[2] = t4.z; uv[3] = t4.w; }

    float sv[4] = {0, 0, 0, 0}, qv[4] = {0, 0, 0, 0};

    const int ITER = 2;
    int blockBase = blockIdx.x * (64 * ITER);
    for (int it = 0; it < ITER; ++it) {
        int gbase = blockBase + it * 64;
        // ---- global loads into regs (overlaps prev Phase C before bar0) ----
        float zr[4][4];
        if (DIN == 64) {
#pragma unroll
            for (int i = 0; i < 4; ++i) {
                int node = gbase + tn * 4 + i;
                float4 xv = {0, 0, 0, 0}, av = {0, 0, 0, 0};
                if (node < N) {
                    xv = *(const float4*)&xin[(size_t)node * 64 + tc * 4];
                    av = *(const float4*)&aggr[(size_t)node * 64 + tc * 4];
                }
                zr[i][0] = fmaf(e1, xv.x, av.x);
                zr[i][1] = fmaf(e1, xv.y, av.y);
                zr[i][2] = fmaf(e1, xv.z, av.z);
                zr[i][3] = fmaf(e1, xv.w, av.w);
            }
        } else {
            int node = gbase + tn * 4 + (tc >> 2);
            float4 xv = {0, 0, 0, 0}, av = {0, 0, 0, 0};
            if (node < N) {
                xv = *(const float4*)&xin[(size_t)node * 16 + (tc & 3) * 4];
                av = *(const float4*)&aggr[(size_t)node * 16 + (tc & 3) * 4];
            }
            zr[0][0] = fmaf(e1, xv.x, av.x);
            zr[0][1] = fmaf(e1, xv.y, av.y);
            zr[0][2] = fmaf(e1, xv.z, av.z);
            zr[0][3] = fmaf(e1, xv.w, av.w);
        }
        float dg[4];
        if (AFF && tid < 64) {
            int node = gbase + tid;
            degS[tid] = (node < N) ? (float)(rs[node + 1] - rs[node]) : 0.0f;
        }
        __syncthreads();                       // bar0: prev iter's t reads done
        if (DIN == 64) {
#pragma unroll
            for (int j = 0; j < 4; ++j) {
                float4 w = {zr[0][j], zr[1][j], zr[2][j], zr[3][j]};
                *(float4*)&zts[(tc * 4 + j) * 68 + tn * 4] = w;
            }
        } else {
#pragma unroll
            for (int j = 0; j < 4; ++j)
                zts[((tc & 3) * 4 + j) * 68 + tn * 4 + (tc >> 2)] = zr[0][j];
        }
        __syncthreads();                       // bar1: z tile ready
        if (AFF) {
#pragma unroll
            for (int i = 0; i < 4; ++i) dg[i] = e1 + degS[tn * 4 + i];
        }
        // ---- Phase B: t = relu(z @ Wa + bias) ----
        float ac[4][4];
#pragma unroll
        for (int i = 0; i < 4; ++i)
#pragma unroll
            for (int j = 0; j < 4; ++j)
                ac[i][j] = AFF ? fmaf(dg[i], uv[j], bav[j]) : bav[j];
#pragma unroll 8
        for (int k = 0; k < DIN; ++k) {
            float4 zv = *(const float4*)&zts[k * 68 + tn * 4];
            float4 wv = *(const float4*)&Wa_s[k * 64 + tc * 4];
            const float zf[4] = {zv.x, zv.y, zv.z, zv.w};
            const float wf[4] = {wv.x, wv.y, wv.z, wv.w};
#pragma unroll
            for (int i = 0; i < 4; ++i)
#pragma unroll
                for (int j = 0; j < 4; ++j)
                    ac[i][j] = fmaf(zf[i], wf[j], ac[i][j]);
        }
#pragma unroll
        for (int i = 0; i < 4; ++i)
#pragma unroll
            for (int j = 0; j < 4; ++j)
                ac[i][j] = fmaxf(ac[i][j], 0.0f);
        __syncthreads();                       // bar2: z tile consumed
#pragma unroll
        for (int j = 0; j < 4; ++j) {
            float4 w = {ac[0][j], ac[1][j], ac[2][j], ac[3][j]};
            *(float4*)&zts[(tc * 4 + j) * 68 + tn * 4] = w;
        }
        __syncthreads();                       // bar3: t tile ready
        // ---- Phase C: h = relu(t @ Wb + bb) ----
        float hc[4][4];
#pragma unroll
        for (int i = 0; i < 4; ++i)
#pragma unroll
            for (int j = 0; j < 4; ++j)
                hc[i][j] = bbv[j];
#pragma unroll 8
        for (int k = 0; k < 64; ++k) {
            float4 tv = *(const float4*)&zts[k * 68 + tn * 4];
            float4 wv = *(const float4*)&Wb_s[k * 64 + tc * 4];
            const float tf[4] = {tv.x, tv.y, tv.z, tv.w};
            const float wf[4] = {wv.x, wv.y, wv.z, wv.w};
#pragma unroll
            for (int i = 0; i < 4; ++i)
#pragma unroll
                for (int j = 0; j < 4; ++j)
                    hc[i][j] = fmaf(tf[i], wf[j], hc[i][j]);
        }
#pragma unroll
        for (int i = 0; i < 4; ++i) {
            int node = gbase + tn * 4 + i;
            if (node < N) {
                float4 o;
                o.x = fmaxf(hc[i][0], 0.0f); o.y = fmaxf(hc[i][1], 0.0f);
                o.z = fmaxf(hc[i][2], 0.0f); o.w = fmaxf(hc[i][3], 0.0f);
                *(float4*)&hout[(size_t)node * 64 + tc * 4] = o;
                sv[0] += o.x; sv[1] += o.y; sv[2] += o.z; sv[3] += o.w;
                qv[0] += o.x * o.x; qv[1] += o.y * o.y; qv[2] += o.z * o.z; qv[3] += o.w * o.w;
            }
        }
    }
    // ---- stats: reduce over tn within wave, then block, then global ----
#pragma unroll
    for (int off = 16; off < 64; off <<= 1) {
#pragma unroll
        for (int j = 0; j < 4; ++j) {
            sv[j] += __shfl_xor(sv[j], off);
            qv[j] += __shfl_xor(qv[j], off);
        }
    }
    if ((tid & 63) < 16) {
#pragma unroll
        for (int j = 0; j < 4; ++j) {
            atomicAdd(&statS[tc * 4 + j], sv[j]);
            atomicAdd(&statS[64 + tc * 4 + j], qv[j]);
        }
    }
    __syncthreads();
    if (tid < 128) unsafeAtomicAdd(&stats[tid], statS[tid]);
}

// ================= segmented pool (batch sorted) =================
__global__ void pool_seg_kernel(const float* __restrict__ h, const int* __restrict__ batch,
                                float* __restrict__ pool, float* __restrict__ cnt, int N) {
    int lane = threadIdx.x & 63;
    int wave = (blockIdx.x * blockDim.x + threadIdx.x) >> 6;
    int base = wave * 16;
    if (base >= N) return;
    int end = base + 16; if (end > N) end = N;
    int cur = batch[base];
    float acc = 0.0f;
    int run = 0;
    for (int n = base; n < end; n++) {
        int gid = batch[n];
        if (gid != cur) {
            unsafeAtomicAdd(&pool[(size_t)cur * 64 + lane], acc);
            if (lane == 0) unsafeAtomicAdd(&cnt[cur], (float)run);
            acc = 0.0f; run = 0; cur = gid;
        }
        acc += h[(size_t)n * 64 + lane];
        run++;
    }
    unsafeAtomicAdd(&pool[(size_t)cur * 64 + lane], acc);
    if (lane == 0) unsafeAtomicAdd(&cnt[cur], (float)run);
}

// ================= readout (applies BN3 affine to pooled mean) =================
__global__ void readout_kernel(const float* __restrict__ pool, const float* __restrict__ cnt,
                               const float* __restrict__ stats, const float* __restrict__ g3,
                               const float* __restrict__ be3,
                               const float* __restrict__ Wf1, const float* __restrict__ bf1,
                               const float* __restrict__ Wf2, const float* __restrict__ bf2,
                               float* __restrict__ out, int N) {
    int gb = blockIdx.x;
    int t = threadIdx.x;  // 64 threads
    float invN = 1.0f / (float)N;
    float mu = stats[t] * invN;
    float var = stats[64 + t] * invN - mu * mu;
    float inv = rsqrtf(var + 1e-5f);
    float a = g3[t] * inv;
    float c = be3[t] - mu * a;
    float cn = cnt[gb];
    float p = (cn > 0.0f) ? (a * (pool[(size_t)gb * 64 + t] / cn) + c) : 0.0f;
    float o = 0.0f;
#pragma unroll
    for (int j = 0; j < 10; j++) {
        float part = p * Wf1[t * 10 + j];
#pragma unroll
        for (int off = 32; off > 0; off >>= 1) part += __shfl_down(part, off);
        float z = fmaxf(part + bf1[j], 0.0f);   // valid on lane 0 only
        o = fmaf(z, Wf2[j], o);
    }
    if (t == 0) out[gb] = o + bf2[0];
}

extern "C" void kernel_launch(void* const* d_in, const int* in_sizes, int n_in,
                              void* d_out, int out_size, void* d_ws, size_t ws_size,
                              hipStream_t stream) {
    const float* x      = (const float*)d_in[0];
    const int*   ei     = (const int*)d_in[1];
    const int*   batch  = (const int*)d_in[2];
    const float* W1a = (const float*)d_in[3];  const float* b1a = (const float*)d_in[4];
    const float* W1b = (const float*)d_in[5];  const float* b1b = (const float*)d_in[6];
    const float* e1  = (const float*)d_in[7];  const float* g1  = (const float*)d_in[8];
    const float* be1 = (const float*)d_in[9];
    const float* W2a = (const float*)d_in[10]; const float* b2a = (const float*)d_in[11];
    const float* W2b = (const float*)d_in[12]; const float* b2b = (const float*)d_in[13];
    const float* e2  = (const float*)d_in[14]; const float* g2  = (const float*)d_in[15];
    const float* be2 = (const float*)d_in[16];
    const float* W3a = (const float*)d_in[17]; const float* b3a = (const float*)d_in[18];
    const float* W3b = (const float*)d_in[19]; const float* b3b = (const float*)d_in[20];
    const float* e3  = (const float*)d_in[21]; const float* g3  = (const float*)d_in[22];
    const float* be3 = (const float*)d_in[23];
    const float* Wf1 = (const float*)d_in[24]; const float* bf1 = (const float*)d_in[25];
    const float* Wf2 = (const float*)d_in[26]; const float* bf2 = (const float*)d_in[27];

    const int N = in_sizes[2];
    const int E = in_sizes[1] / 2;
    const int G = out_size;

    // ---------- workspace layout ----------
    int* csr       = (int*)d_ws;                 // E
    int* row_start = csr + E;                    // N+1 (+pad)
    int* deg       = row_start + N + 64;         // N
    int* cursor    = deg + N;                    // N
    int* bsum      = cursor + N;                 // 256
    int* boff      = bsum + 256;                 // 256
    float* fbase   = (float*)(boff + 256);
    size_t NH = (size_t)N * HD;
    float* aggr   = fbase;                       // N*64
    float* hA     = aggr + NH;                   // N*64
    float* hB     = hA + NH;                     // N*64
    float* stats  = hB + NH;                     // 3*128
    float* WaEff2 = stats + 384;                 // 4096
    float* u2     = WaEff2 + 4096;               // 64
    float* WaEff3 = u2 + 64;                     // 4096
    float* u3     = WaEff3 + 4096;               // 64
    float* pool   = u3 + 64;                     // G*64
    float* cnt    = pool + (size_t)G * HD;       // G

    const int TB = 256;
    int nb = (N + 1023) / 1024;
    int fusedGrid = (N + 127) / 128;

    // ---------- CSR build ----------
    hipMemsetAsync(deg, 0, 2 * (size_t)N * sizeof(int), stream);   // deg + cursor
    hipMemsetAsync(stats, 0, 384 * sizeof(float), stream);
    hipMemsetAsync(pool, 0, ((size_t)G * HD + G) * sizeof(float), stream);
    degree_kernel<<<(E + TB - 1) / TB, TB, 0, stream>>>(ei, deg, E);
    blocksum_kernel<<<nb, TB, 0, stream>>>(deg, bsum, N);
    scansums_kernel<<<1, 64, 0, stream>>>(bsum, boff, nb);
    scanwrite_kernel<<<nb, TB, 0, stream>>>(deg, boff, row_start, N);
    fill_kernel<<<(E + TB - 1) / TB, TB, 0, stream>>>(ei, row_start, cursor, csr, E);

    // ---------- layer 1: x(16) -> hA (raw pre-BN h1), stats1 ----------
    gather16_kernel<<<((N + 15) / 16 * 64 + TB - 1) / TB, TB, 0, stream>>>(x, row_start, csr, aggr, N);
    fused_mlp_kernel<16, false><<<fusedGrid, TB, 0, stream>>>(
        x, aggr, row_start, W1a, b1a, nullptr, W1b, b1b, e1, hA, stats, N);

    // ---------- layer 2: hA(raw) -> hB, BN1 folded via WaEff2/u2 ----------
    prep_kernel<<<1, 256, 0, stream>>>(stats, g1, be1, W2a, WaEff2, u2, N);
    gather64_kernel<<<((N + 3) / 4 * 64 + TB - 1) / TB, TB, 0, stream>>>(hA, row_start, csr, aggr, N);
    fused_mlp_kernel<64, true><<<fusedGrid, TB, 0, stream>>>(
        hA, aggr, row_start, WaEff2, b2a, u2, W2b, b2b, e2, hB, stats + 128, N);

    // ---------- layer 3: hB(raw) -> hA, BN2 folded via WaEff3/u3 ----------
    prep_kernel<<<1, 256, 0, stream>>>(stats + 128, g2, be2, W3a, WaEff3, u3, N);
    gather64_kernel<<<((N + 3) / 4 * 64 + TB - 1) / TB, TB, 0, stream>>>(hB, row_start, csr, aggr, N);
    fused_mlp_kernel<64, true><<<fusedGrid, TB, 0, stream>>>(
        hB, aggr, row_start, WaEff3, b3a, u3, W3b, b3b, e3, hA, stats + 256, N);

    // ---------- pool raw h3 (BN3 affine applied in readout) ----------
    int poolWaves = (N + 15) / 16;
    pool_seg_kernel<<<(poolWaves * 64 + TB - 1) / TB, TB, 0, stream>>>(hA, batch, pool, cnt, N);
    readout_kernel<<<G, 64, 0, stream>>>(pool, cnt, stats + 256, g3, be3,
                                         Wf1, bf1, Wf2, bf2, (float*)d_out, N);
}